// Round 13
// baseline (27.601 us; speedup 1.0000x reference)
//
#include <hip/hip_runtime.h>

// AffinityFeature, symmetric formulation. R13: FORCED-MLP + VMEM-thin.
// Same mapping/epilogue as R2 (best 24.9us). Changes:
//  - 8-channel load batches into statically-indexed register arrays, fenced
//    by sched_barrier(0): 16 float4 loads in flight per wave (vs ~2-3).
//  - Edge values (w0+4 / w0-1 cols) via __shfl from the adjacent lane's
//    float4 instead of 3 divergent scalar loads per channel; only lanes
//    0/63 issue masked 2-active-lane boundary loads. VMEM wave-instructions
//    per channel: 5 -> 2 (+3 thin).

#define AF_B 4
#define AF_C 32
#define AF_H 256
#define AF_W 512
#define AF_EPS 1e-12f
#define AF_PLANE ((size_t)AF_H * AF_W)
#define CB 8

__global__ __launch_bounds__(256) void affinity_mlp_kernel(const float* __restrict__ f,
                                                           float* __restrict__ out) {
    // XCD-aware swizzle: 512 blocks -> 64-block contiguous slab per XCD
    const int cpx = gridDim.x >> 3;
    const int bid = ((int)blockIdx.x & 7) * cpx + ((int)blockIdx.x >> 3);

    const int tid = (int)threadIdx.x;
    const int G = bid * 256 + tid;          // pixel-group id (4 px each)
    const int w0 = (G & 127) << 2;          // 0..508; wave = 64 contiguous groups
    const int rowIdx = G >> 7;
    const int h = rowIdx & (AF_H - 1);
    const int b = rowIdx >> 8;
    const int lane = tid & 63;

    const bool vS = (h + 1) < AF_H;
    const bool vR = (w0 + 4) < AF_W;
    const bool vL = w0 > 0;
    const float mS = vS ? 1.0f : 0.0f;      // uniform per wave
    const bool bR = (lane == 63) && vR;     // right boundary lane loads
    const bool bL = (lane == 0) && vL;      // left boundary lane load

    const float* pc = f + (size_t)b * AF_C * AF_PLANE + (size_t)h * AF_W + w0;
    const float* ps = pc + (vS ? AF_W : 0);

    float ssq0=0,ssq1=0,ssq2=0,ssq3=0, ssqR=0;
    float nsq0=0,nsq1=0,nsq2=0,nsq3=0, nsqL=0,nsqR=0;
    float dE0=0,dE1=0,dE2=0,dE3=0;
    float dS0=0,dS1=0,dS2=0,dS3=0;
    float dSE0=0,dSE1=0,dSE2=0,dSE3=0;
    float dSW0=0,dSW1=0,dSW2=0,dSW3=0;

#pragma unroll
    for (int gb = 0; gb < AF_C / CB; ++gb) {
        // ---- batched issue: 16 float4 + 24 thin boundary loads ----
        float4 cc[CB], cs[CB];
        float eR[CB], eS[CB], eL[CB];
#pragma unroll
        for (int k = 0; k < CB; ++k) {
            const float* p = pc + (size_t)k * AF_PLANE;
            const float* q = ps + (size_t)k * AF_PLANE;
            cc[k] = *(const float4*)p;
            cs[k] = *(const float4*)q;
            eR[k] = bR ? p[4]  : 0.0f;   // center col w0+4 (lane 63 only)
            eS[k] = bR ? q[4]  : 0.0f;   // south  col w0+4 (lane 63 only)
            eL[k] = bL ? q[-1] : 0.0f;   // south  col w0-1 (lane 0 only)
        }
        __builtin_amdgcn_sched_barrier(0);   // keep the batch clustered

        // ---- consume: edges via cross-lane shuffle ----
#pragma unroll
        for (int k = 0; k < CB; ++k) {
            const float sh_ccx = __shfl(cc[k].x, lane + 1);
            const float sh_csx = __shfl(cs[k].x, lane + 1);
            const float sh_csw = __shfl(cs[k].w, lane - 1);

            const float ccx = cc[k].x, ccy = cc[k].y, ccz = cc[k].z, ccw = cc[k].w;
            const float ccR = (lane == 63) ? eR[k] : sh_ccx;
            const float csx = cs[k].x * mS, csy = cs[k].y * mS,
                        csz = cs[k].z * mS, csw = cs[k].w * mS;
            const float csR = ((lane == 63) ? eS[k] : sh_csx) * mS;
            const float csL = ((lane == 0)  ? eL[k] : sh_csw) * mS;

            ssq0 += ccx*ccx; ssq1 += ccy*ccy; ssq2 += ccz*ccz; ssq3 += ccw*ccw;
            ssqR += ccR*ccR;
            nsq0 += csx*csx; nsq1 += csy*csy; nsq2 += csz*csz; nsq3 += csw*csw;
            nsqL += csL*csL; nsqR += csR*csR;
            dE0 += ccx*ccy;  dE1 += ccy*ccz;  dE2 += ccz*ccw;  dE3 += ccw*ccR;
            dS0 += ccx*csx;  dS1 += ccy*csy;  dS2 += ccz*csz;  dS3 += ccw*csw;
            dSE0 += ccx*csy; dSE1 += ccy*csz; dSE2 += ccz*csw; dSE3 += ccw*csR;
            dSW0 += ccx*csL; dSW1 += ccy*csx; dSW2 += ccz*csy; dSW3 += ccw*csz;
        }
        pc += (size_t)CB * AF_PLANE;
        ps += (size_t)CB * AF_PLANE;
    }

    const float ic0 = 1.0f / fmaxf(sqrtf(ssq0), AF_EPS);
    const float ic1 = 1.0f / fmaxf(sqrtf(ssq1), AF_EPS);
    const float ic2 = 1.0f / fmaxf(sqrtf(ssq2), AF_EPS);
    const float ic3 = 1.0f / fmaxf(sqrtf(ssq3), AF_EPS);
    const float icR = 1.0f / fmaxf(sqrtf(ssqR), AF_EPS);
    const float is0 = 1.0f / fmaxf(sqrtf(nsq0), AF_EPS);
    const float is1 = 1.0f / fmaxf(sqrtf(nsq1), AF_EPS);
    const float is2 = 1.0f / fmaxf(sqrtf(nsq2), AF_EPS);
    const float is3 = 1.0f / fmaxf(sqrtf(nsq3), AF_EPS);
    const float isL = 1.0f / fmaxf(sqrtf(nsqL), AF_EPS);
    const float isR = 1.0f / fmaxf(sqrtf(nsqR), AF_EPS);

    const float E0 = fmaxf(dE0*ic0*ic1, 0.0f);
    const float E1 = fmaxf(dE1*ic1*ic2, 0.0f);
    const float E2 = fmaxf(dE2*ic2*ic3, 0.0f);
    const float E3 = fmaxf(dE3*ic3*icR, 0.0f);
    const float S0 = fmaxf(dS0*ic0*is0, 0.0f);
    const float S1 = fmaxf(dS1*ic1*is1, 0.0f);
    const float S2 = fmaxf(dS2*ic2*is2, 0.0f);
    const float S3 = fmaxf(dS3*ic3*is3, 0.0f);
    const float SE0 = fmaxf(dSE0*ic0*is1, 0.0f);
    const float SE1 = fmaxf(dSE1*ic1*is2, 0.0f);
    const float SE2 = fmaxf(dSE2*ic2*is3, 0.0f);
    const float SE3 = fmaxf(dSE3*ic3*isR, 0.0f);
    const float SW0 = fmaxf(dSW0*ic0*isL, 0.0f);
    const float SW1 = fmaxf(dSW1*ic1*is0, 0.0f);
    const float SW2 = fmaxf(dSW2*ic2*is1, 0.0f);
    const float SW3 = fmaxf(dSW3*ic3*is2, 0.0f);

    float* ob = out + (size_t)b * 8 * AF_PLANE + (size_t)h * AF_W + w0;

    // forward channels at (h, w0..w0+3), aligned float4
    *(float4*)(ob + 4*AF_PLANE) = make_float4(E0,E1,E2,E3);
    *(float4*)(ob + 6*AF_PLANE) = make_float4(S0,S1,S2,S3);
    *(float4*)(ob + 7*AF_PLANE) = make_float4(SE0,SE1,SE2,SE3);
    *(float4*)(ob + 5*AF_PLANE) = make_float4(SW0,SW1,SW2,SW3);

    // a=3 (W) at (h, w0+1..w0+4)
    float* o3 = ob + 3*AF_PLANE;
    o3[1] = E0; o3[2] = E1; o3[3] = E2;
    if (vR) o3[4] = E3;
    if (!vL) o3[0] = 0.0f;      // W of (h,0) OOB

    if (vS) {
        float* on = ob + AF_W;  // row h+1, col w0
        *(float4*)(on + 1*AF_PLANE) = make_float4(S0,S1,S2,S3);   // N
        float* o0 = on;         // NW(h+1,w) = SE(h,w-1)
        o0[1] = SE0; o0[2] = SE1; o0[3] = SE2;
        if (vR) o0[4] = SE3;
        if (!vL) o0[0] = 0.0f;
        float* o2 = on + 2*AF_PLANE;   // NE(h+1,w) = SW(h,w+1)
        if (vL) o2[-1] = SW0;
        o2[0] = SW1; o2[1] = SW2; o2[2] = SW3;
        if (!vR) o2[3] = 0.0f;
    }

    if (h == 0) {               // N/NW/NE rows at h=0 are all OOB -> zero
        float* oz = out + (size_t)b * 8 * AF_PLANE + w0;
        const float4 z4 = make_float4(0.0f, 0.0f, 0.0f, 0.0f);
        *(float4*)(oz + 0*AF_PLANE) = z4;
        *(float4*)(oz + 1*AF_PLANE) = z4;
        *(float4*)(oz + 2*AF_PLANE) = z4;
    }
}

extern "C" void kernel_launch(void* const* d_in, const int* in_sizes, int n_in,
                              void* d_out, int out_size, void* d_ws, size_t ws_size,
                              hipStream_t stream) {
    const float* f = (const float*)d_in[0];
    float* out = (float*)d_out;
    // 512 blocks x 256 threads; 4 px/thread
    affinity_mlp_kernel<<<512, 256, 0, stream>>>(f, out);
}